// Round 9
// baseline (704.822 us; speedup 1.0000x reference)
//
#include <hip/hip_runtime.h>
#include <hip/hip_bf16.h>

#define S_LEN 2048
#define E_DIM 1024
#define D_DIM 1024

typedef __bf16 bf16x8 __attribute__((ext_vector_type(8)));
typedef __bf16 bf16x4 __attribute__((ext_vector_type(4)));
typedef float f32x4 __attribute__((ext_vector_type(4)));

__device__ __forceinline__ __bf16 f2bf(float f) {
    unsigned u = __builtin_bit_cast(unsigned, f);
    u += 0x7fffu + ((u >> 16) & 1u);
    unsigned short h = (unsigned short)(u >> 16);
    return __builtin_bit_cast(__bf16, h);
}

// Read-side swizzle: rows are 128 B; XOR byte bits 4-6 with row&7.
__device__ __forceinline__ int swz(int row, int b) {
    return row * 128 + (b ^ ((row & 7) << 4));
}

// Async global->LDS, 16 B/lane. LDS dest = wave-uniform base + lane*16.
__device__ __forceinline__ void async_cp16(void* lds, const void* g) {
    __builtin_amdgcn_global_load_lds(
        (const __attribute__((address_space(1))) void*)g,
        (__attribute__((address_space(3))) void*)lds, 16, 0, 0);
}

// Stage one half-tile (128 rows x 128 B) into linear LDS; global source column
// pre-XOR'd by row&7 (both-sides swizzle involution). 2 gload_lds per wave.
__device__ __forceinline__ void stage_half(char* halfBase, const char* gRow0,
                                           size_t strideB, int tid)
{
    const int r  = tid >> 3;            // 0..63
    const int cb = (tid & 7) * 16;
    const int sc = cb ^ ((r & 7) << 4);
    #pragma unroll
    for (int i = 0; i < 2; ++i) {
        async_cp16(halfBase + i * 8192 + ((tid >> 6) << 10),
                   gRow0 + (size_t)(i * 64 + r) * strideB + sc);
    }
}

// Fragment loads: A-half H -> a[4][2] (8 ds_read_b128); B-half H -> b2 (4).
template<int H>
__device__ __forceinline__ void loadA(const char* lsA, int wrr, int rl, int lh,
                                      bf16x8 (&a)[4][2])
{
    #pragma unroll
    for (int mi = 0; mi < 4; ++mi)
        #pragma unroll
        for (int ks = 0; ks < 2; ++ks)
            a[mi][ks] = *reinterpret_cast<const bf16x8*>(
                lsA + swz(H*128 + wrr*64 + mi*16 + rl, ks*64 + lh*16));
}
template<int H>
__device__ __forceinline__ void loadB(const char* lsB, int wcc, int rl, int lh,
                                      bf16x8 (&b2)[2][2])
{
    #pragma unroll
    for (int ni = 0; ni < 2; ++ni)
        #pragma unroll
        for (int ks = 0; ks < 2; ++ks)
            b2[ni][ks] = *reinterpret_cast<const bf16x8*>(
                lsB + swz(H*128 + wcc*32 + ni*16 + rl, ks*64 + lh*16));
}

// Closed MFMA region: barrier -> lgkm0 -> prio1 -> 16 MFMA -> prio0 -> barrier.
#define MFMA_REGION(QM, QN, BSLOT)                                               \
    do {                                                                         \
        __builtin_amdgcn_s_barrier();                                            \
        asm volatile("s_waitcnt lgkmcnt(0)" ::: "memory");                       \
        __builtin_amdgcn_sched_barrier(0);                                       \
        __builtin_amdgcn_s_setprio(1);                                           \
        _Pragma("unroll")                                                        \
        for (int mi = 0; mi < 4; ++mi)                                           \
            _Pragma("unroll")                                                    \
            for (int ni = 0; ni < 2; ++ni)                                       \
                _Pragma("unroll")                                                \
                for (int ks = 0; ks < 2; ++ks)                                   \
                    acc[(QM)*2+(QN)][mi][ni] =                                   \
                        __builtin_amdgcn_mfma_f32_16x16x32_bf16(                 \
                            a[mi][ks], BSLOT[ni][ks],                            \
                            acc[(QM)*2+(QN)][mi][ni], 0, 0, 0);                  \
        __builtin_amdgcn_s_setprio(0);                                           \
        __builtin_amdgcn_s_barrier();                                            \
    } while (0)

#define VMCNT(n) asm volatile("s_waitcnt vmcnt(" #n ")" ::: "memory")

// 256x256xK GEMM core. Phase order (0,0),(0,1),(1,1),(1,0); stages (A0+B0)@P1,
// B1@P2, A1@P3 -> >=3-phase flight per half; waits P1:6 P2:6 P4:4 (steady),
// always before a barrier. nt >= 2.
__device__ __forceinline__ void gemm256(const char* gA, const char* gB,
    size_t sA, size_t sB, int nt, char* ls, f32x4 (&acc)[4][4][2])
{
    const int tid = threadIdx.x, lane = tid & 63, wid = tid >> 6;
    const int wrr = wid >> 2, wcc = wid & 3;
    const int rl = lane & 15, lh = lane >> 4;
    char* bufA[2] = { ls,         ls + 65536 };
    char* bufB[2] = { ls + 32768, ls + 98304 };

    bf16x8 a[4][2];
    bf16x8 bb[2][2][2];   // bb[0]=B-half0 frags, bb[1]=B-half1 frags

    // prologue: tile 0 (S1=A0, S2=B0, S3=B1, S4=A1); land S1,S2 before P1 reads
    stage_half(bufA[0] + 0,     gA,                    sA, tid);
    stage_half(bufB[0] + 0,     gB,                    sB, tid);
    stage_half(bufB[0] + 16384, gB + (size_t)128 * sB, sB, tid);
    stage_half(bufA[0] + 16384, gA + (size_t)128 * sA, sA, tid);
    VMCNT(4);
    __builtin_amdgcn_s_barrier();

    for (int u = 0; u < nt - 1; ++u) {
        const char* cA = bufA[u & 1];
        const char* cB = bufB[u & 1];
        char* nA = bufA[(u + 1) & 1];
        char* nB = bufB[(u + 1) & 1];
        const char* gAn = gA + (size_t)(u + 1) * 128;
        const char* gBn = gB + (size_t)(u + 1) * 128;

        // P1: reads A0,B0; stage next A0+B0; wait covers P2's B1 (oldest)
        loadA<0>(cA, wrr, rl, lh, a);
        loadB<0>(cB, wcc, rl, lh, bb[0]);
        stage_half(nA + 0, gAn, sA, tid);
        stage_half(nB + 0, gBn, sB, tid);
        VMCNT(6);
        MFMA_REGION(0, 0, bb[0]);

        // P2: reads B1; stage next B1; wait covers P3's A1
        loadB<1>(cB, wcc, rl, lh, bb[1]);
        stage_half(nB + 16384, gBn + (size_t)128 * sB, sB, tid);
        VMCNT(6);
        MFMA_REGION(0, 1, bb[1]);

        // P3: reads A1; stage next A1; P4 needs nothing -> no wait
        loadA<1>(cA, wrr, rl, lh, a);
        stage_half(nA + 16384, gAn + (size_t)128 * sA, sA, tid);
        MFMA_REGION(1, 1, bb[1]);

        // P4: no reads; wait covers next window P1's A0,B0
        VMCNT(4);
        MFMA_REGION(1, 0, bb[0]);
    }

    // final window: no staging; drain counted
    {
        const char* cA = bufA[(nt - 1) & 1];
        const char* cB = bufB[(nt - 1) & 1];

        loadA<0>(cA, wrr, rl, lh, a);
        loadB<0>(cB, wcc, rl, lh, bb[0]);
        VMCNT(2);                       // land B1
        MFMA_REGION(0, 0, bb[0]);

        loadB<1>(cB, wcc, rl, lh, bb[1]);
        VMCNT(0);                       // land A1
        MFMA_REGION(0, 1, bb[1]);

        loadA<1>(cA, wrr, rl, lh, a);
        MFMA_REGION(1, 1, bb[1]);

        MFMA_REGION(1, 0, bb[0]);
    }
}

// Epilogue index helpers: for quadrant q (QM=q>>1, QN=q&1):
//   row = QM*128 + (wid>>2)*64 + mi*16 + lh*4 + r
//   col = QN*128 + (wid&3)*32 + ni*16 + rl

// ---------------- K0a: X (f32) -> Xb (bf16), flat ----------------------------
__global__ __launch_bounds__(256) void cvt_x_kernel(
    const float* __restrict__ X, __bf16* __restrict__ Xb)
{
    const int n8 = (8 * S_LEN * E_DIM) / 8;
    for (int i = blockIdx.x * 256 + threadIdx.x; i < n8; i += gridDim.x * 256) {
        const float* p = X + (size_t)i * 8;
        float4 a = *reinterpret_cast<const float4*>(p);
        float4 b = *reinterpret_cast<const float4*>(p + 4);
        bf16x8 h = { f2bf(a.x), f2bf(a.y), f2bf(a.z), f2bf(a.w),
                     f2bf(b.x), f2bf(b.y), f2bf(b.z), f2bf(b.w) };
        *reinterpret_cast<bf16x8*>(Xb + (size_t)i * 8) = h;
    }
}

// ---------------- K0b: W (f32 [E][D]) -> Wt (bf16 [D][E]), 3 slices ----------
__global__ __launch_bounds__(256) void wt_kernel(
    const float* __restrict__ Wq, const float* __restrict__ Wk, const float* __restrict__ Wv,
    __bf16* __restrict__ Wt)
{
    __shared__ float t[64][68];
    const int z = blockIdx.z;
    const float* W = (z == 0) ? Wq : (z == 1) ? Wk : Wv;
    const int d0 = blockIdx.x * 64, e0 = blockIdx.y * 64;
    const int tid = threadIdx.x;

    const int er = tid >> 4, dc = (tid & 15) * 4;
    #pragma unroll
    for (int p = 0; p < 4; ++p) {
        int e = p * 16 + er;
        float4 v = *reinterpret_cast<const float4*>(W + (size_t)(e0 + e) * D_DIM + d0 + dc);
        *reinterpret_cast<float4*>(&t[e][dc]) = v;
    }
    __syncthreads();

    const int dl = tid >> 3, ec = (tid & 7) * 8;
    __bf16* O = Wt + (size_t)z * E_DIM * D_DIM;
    #pragma unroll
    for (int p = 0; p < 2; ++p) {
        int d = p * 32 + dl;
        bf16x8 h;
        #pragma unroll
        for (int j = 0; j < 8; ++j) h[j] = f2bf(t[ec + j][d]);
        *reinterpret_cast<bf16x8*>(O + (size_t)(d0 + d) * E_DIM + e0 + ec) = h;
    }
}

// ---------------- K1: QKV projection (V stored transposed) -------------------
__global__ __launch_bounds__(512, 2) void qkv_kernel(
    const __bf16* __restrict__ Xb, const __bf16* __restrict__ Wt,
    __bf16* __restrict__ Qb, __bf16* __restrict__ Kb, __bf16* __restrict__ Vt)
{
    __shared__ __align__(16) char ls[131072];
    const int bx = blockIdx.x, mt = blockIdx.y, z = blockIdx.z;
    const int m0 = mt * 256, n0 = bx * 256;

    f32x4 acc[4][4][2] = {};
    gemm256((const char*)Xb + (size_t)m0 * (E_DIM * 2),
            (const char*)(Wt + (size_t)z * E_DIM * D_DIM) + (size_t)n0 * (E_DIM * 2),
            E_DIM * 2, E_DIM * 2, E_DIM / 64, ls, acc);

    const int tid = threadIdx.x, lane = tid & 63, wid = tid >> 6;
    const int wrr = wid >> 2, wcc = wid & 3;
    const int rl = lane & 15, lh = lane >> 4;

    if (z < 2) {
        __bf16* O = (z == 0) ? Qb : Kb;
        #pragma unroll
        for (int q = 0; q < 4; ++q) {
            #pragma unroll
            for (int mi = 0; mi < 4; ++mi) {
                int row = m0 + (q >> 1)*128 + wrr*64 + mi*16 + lh*4;
                #pragma unroll
                for (int ni = 0; ni < 2; ++ni) {
                    int col = n0 + (q & 1)*128 + wcc*32 + ni*16 + rl;
                    #pragma unroll
                    for (int r = 0; r < 4; ++r)
                        O[(size_t)(row + r) * D_DIM + col] = f2bf(acc[q][mi][ni][r]);
                }
            }
        }
    } else {
        const int bz = m0 >> 11;
        const int srow = m0 & 2047;
        __bf16* O = Vt + (size_t)bz * D_DIM * S_LEN;
        #pragma unroll
        for (int q = 0; q < 4; ++q) {
            #pragma unroll
            for (int mi = 0; mi < 4; ++mi) {
                int row = srow + (q >> 1)*128 + wrr*64 + mi*16 + lh*4;
                #pragma unroll
                for (int ni = 0; ni < 2; ++ni) {
                    int col = n0 + (q & 1)*128 + wcc*32 + ni*16 + rl;
                    bf16x4 h = { f2bf(acc[q][mi][ni][0]), f2bf(acc[q][mi][ni][1]),
                                 f2bf(acc[q][mi][ni][2]), f2bf(acc[q][mi][ni][3]) };
                    *reinterpret_cast<bf16x4*>(O + (size_t)col * S_LEN + row) = h;
                }
            }
        }
    }
}

// ---------------- K2: scores = QK^T/32, P = mask*exp(s), rowsums -------------
__global__ __launch_bounds__(512, 2) void qk_kernel(
    const __bf16* __restrict__ Qb, const __bf16* __restrict__ Kb,
    const int* __restrict__ mask, __bf16* __restrict__ P, float* __restrict__ rowsum)
{
    __shared__ __align__(16) char ls[131072];
    const int kt = blockIdx.x, qt = blockIdx.y, bz = blockIdx.z;
    const int q0 = qt * 256, k0 = kt * 256;

    f32x4 acc[4][4][2] = {};
    gemm256((const char*)(Qb + (size_t)bz * S_LEN * D_DIM) + (size_t)q0 * (D_DIM * 2),
            (const char*)(Kb + (size_t)bz * S_LEN * D_DIM) + (size_t)k0 * (D_DIM * 2),
            D_DIM * 2, D_DIM * 2, D_DIM / 64, ls, acc);

    const int tid = threadIdx.x, lane = tid & 63, wid = tid >> 6;
    const int wrr = wid >> 2, wcc = wid & 3;
    const int rl = lane & 15, lh = lane >> 4;

    float rs[2][4][4] = {};
    const size_t mbase = (size_t)bz * S_LEN * S_LEN;
    #pragma unroll
    for (int q = 0; q < 4; ++q) {
        #pragma unroll
        for (int mi = 0; mi < 4; ++mi) {
            int row = q0 + (q >> 1)*128 + wrr*64 + mi*16 + lh*4;
            #pragma unroll
            for (int ni = 0; ni < 2; ++ni) {
                int col = k0 + (q & 1)*128 + wcc*32 + ni*16 + rl;
                #pragma unroll
                for (int r = 0; r < 4; ++r) {
                    float s = acc[q][mi][ni][r] * 0.03125f;
                    int mk = mask[mbase + (size_t)(row + r) * S_LEN + col];
                    float pv = mk ? __expf(s) : 0.0f;
                    rs[q >> 1][mi][r] += pv;
                    P[mbase + (size_t)(row + r) * S_LEN + col] = f2bf(pv);
                }
            }
        }
    }
    #pragma unroll
    for (int h = 0; h < 2; ++h) {
        #pragma unroll
        for (int mi = 0; mi < 4; ++mi) {
            #pragma unroll
            for (int r = 0; r < 4; ++r) {
                float v = rs[h][mi][r];
                v += __shfl_xor(v, 1);
                v += __shfl_xor(v, 2);
                v += __shfl_xor(v, 4);
                v += __shfl_xor(v, 8);
                if (rl == 0)
                    atomicAdd(&rowsum[bz * S_LEN + q0 + h*128 + wrr*64 + mi*16 + lh*4 + r], v);
            }
        }
    }
}

// ---------------- K3: out = (P @ V) / rowsum ---------------------------------
__global__ __launch_bounds__(512, 2) void pv_kernel(
    const __bf16* __restrict__ P, const __bf16* __restrict__ Vt,
    const float* __restrict__ rowsum, float* __restrict__ out)
{
    __shared__ __align__(16) char ls[131072];
    const int dt = blockIdx.x, qt = blockIdx.y, bz = blockIdx.z;
    const int q0 = qt * 256, d0c = dt * 256;

    f32x4 acc[4][4][2] = {};
    gemm256((const char*)(P  + (size_t)bz * S_LEN * S_LEN) + (size_t)q0  * (S_LEN * 2),
            (const char*)(Vt + (size_t)bz * D_DIM * S_LEN) + (size_t)d0c * (S_LEN * 2),
            S_LEN * 2, S_LEN * 2, S_LEN / 64, ls, acc);

    const int tid = threadIdx.x, lane = tid & 63, wid = tid >> 6;
    const int wrr = wid >> 2, wcc = wid & 3;
    const int rl = lane & 15, lh = lane >> 4;

    float* Ob = out + (size_t)bz * S_LEN * D_DIM;
    #pragma unroll
    for (int q = 0; q < 4; ++q) {
        #pragma unroll
        for (int mi = 0; mi < 4; ++mi) {
            int row = q0 + (q >> 1)*128 + wrr*64 + mi*16 + lh*4;
            float inv[4];
            #pragma unroll
            for (int r = 0; r < 4; ++r)
                inv[r] = 1.0f / (rowsum[bz * S_LEN + row + r] + 1e-20f);
            #pragma unroll
            for (int ni = 0; ni < 2; ++ni) {
                int col = d0c + (q & 1)*128 + wcc*32 + ni*16 + rl;
                #pragma unroll
                for (int r = 0; r < 4; ++r)
                    Ob[(size_t)(row + r) * D_DIM + col] = acc[q][mi][ni][r] * inv[r];
            }
        }
    }
}

extern "C" void kernel_launch(void* const* d_in, const int* in_sizes, int n_in,
                              void* d_out, int out_size, void* d_ws, size_t ws_size,
                              hipStream_t stream) {
    const float* x    = (const float*)d_in[0];
    const int*   mask = (const int*)  d_in[1];
    const float* Wq   = (const float*)d_in[2];
    const float* Wk   = (const float*)d_in[3];
    const float* Wv   = (const float*)d_in[4];
    float* out = (float*)d_out;

    char* ws = (char*)d_ws;
    const size_t SZ_QKV = (size_t)8 * S_LEN * D_DIM * 2;      // 32 MB each (bf16)
    const size_t SZ_P   = (size_t)8 * S_LEN * S_LEN * 2;      // 64 MB
    __bf16* Qb = (__bf16*)(ws);
    __bf16* Kb = (__bf16*)(ws + SZ_QKV);
    __bf16* Vt = (__bf16*)(ws + 2 * SZ_QKV);
    char*   pbase = ws + 3 * SZ_QKV;
    __bf16* P  = (__bf16*)pbase;
    // Xb/Wt alias the P region: fully consumed by qkv_kernel before qk_kernel
    // writes P (stream-ordered), saves 38 MB.
    __bf16* Xb = (__bf16*)pbase;                              // 32 MB
    __bf16* Wt = (__bf16*)(pbase + (size_t)8 * S_LEN * E_DIM * 2);  // 6 MB
    float* rowsum = (float*)(ws + 3 * SZ_QKV + SZ_P);
    const size_t need = 3 * SZ_QKV + SZ_P + (size_t)8 * S_LEN * 4;
    if (ws_size < need) return;

    hipMemsetAsync(rowsum, 0, (size_t)8 * S_LEN * 4, stream);
    cvt_x_kernel<<<2048, 256, 0, stream>>>(x, Xb);
    wt_kernel  <<<dim3(16, 16, 3), 256, 0, stream>>>(Wq, Wk, Wv, Wt);
    qkv_kernel <<<dim3(4, 64, 3), 512, 0, stream>>>(Xb, Wt, Qb, Kb, Vt);
    qk_kernel  <<<dim3(8, 8, 8),  512, 0, stream>>>(Qb, Kb, mask, P, rowsum);
    pv_kernel  <<<dim3(4, 8, 8),  512, 0, stream>>>(P, Vt, rowsum, out);
}

// Round 10
// 560.383 us; speedup vs baseline: 1.2578x; 1.2578x over previous
//
#include <hip/hip_runtime.h>
#include <hip/hip_bf16.h>

#define S_LEN 2048
#define E_DIM 1024
#define D_DIM 1024

typedef __bf16 bf16x8 __attribute__((ext_vector_type(8)));
typedef __bf16 bf16x4 __attribute__((ext_vector_type(4)));
typedef float f32x4 __attribute__((ext_vector_type(4)));

__device__ __forceinline__ __bf16 f2bf(float f) {
    unsigned u = __builtin_bit_cast(unsigned, f);
    u += 0x7fffu + ((u >> 16) & 1u);
    unsigned short h = (unsigned short)(u >> 16);
    return __builtin_bit_cast(__bf16, h);
}

// Read-side swizzle: rows are 128 B; XOR byte bits 4-6 with row&7.
__device__ __forceinline__ int swz(int row, int b) {
    return row * 128 + (b ^ ((row & 7) << 4));
}

// Bijective XCD swizzle (m204): hardware-consecutive blocks round-robin XCDs;
// remap so each XCD owns a contiguous chunk of logical tile space.
__device__ __forceinline__ void xcd_map(int gx, int gy, int gz,
                                        int& lx, int& ly, int& lz)
{
    const int flat = blockIdx.x + gx * (blockIdx.y + gy * blockIdx.z);
    const int q = (gx * gy * gz) >> 3;          // nwg/8, nwg%8==0 everywhere
    const int l = (flat & 7) * q + (flat >> 3);
    lx = l % gx; const int t = l / gx; ly = t % gy; lz = t / gy;
}

// Async global->LDS, 16 B/lane. LDS dest = wave-uniform base + lane*16.
__device__ __forceinline__ void async_cp16(void* lds, const void* g) {
    __builtin_amdgcn_global_load_lds(
        (const __attribute__((address_space(1))) void*)g,
        (__attribute__((address_space(3))) void*)lds, 16, 0, 0);
}

// Stage one half-tile (128 rows x 128 B) into linear LDS; global source column
// pre-XOR'd by row&7 (both-sides swizzle involution). 2 gload_lds per wave.
__device__ __forceinline__ void stage_half(char* halfBase, const char* gRow0,
                                           size_t strideB, int tid)
{
    const int r  = tid >> 3;            // 0..63
    const int cb = (tid & 7) * 16;
    const int sc = cb ^ ((r & 7) << 4);
    #pragma unroll
    for (int i = 0; i < 2; ++i) {
        async_cp16(halfBase + i * 8192 + ((tid >> 6) << 10),
                   gRow0 + (size_t)(i * 64 + r) * strideB + sc);
    }
}

#define PEND(n) do { asm volatile("s_waitcnt vmcnt(" #n ")" ::: "memory"); \
                     __builtin_amdgcn_s_barrier(); } while (0)

// One phase: all 8 waves compute C-quadrant (QM,QN) of the 256x256 tile,
// K=64 -> 16 MFMA/wave. A/B fragments optionally loaded (reused otherwise).
// No hard lgkmcnt/sched_barrier: compiler emits fine-grained per-read waits
// (r9 measured: pinning this regresses 562 -> 705).
template<int QM, int QN, bool LA, bool LB>
__device__ __forceinline__ void phase8(const char* lsA, const char* lsB,
    int wrr, int wcc, int rl, int lh,
    bf16x8 (&a)[4][2], bf16x8 (&b)[2][2], f32x4 (&acc)[4][4][2])
{
    if (LA) {
        #pragma unroll
        for (int mi = 0; mi < 4; ++mi)
            #pragma unroll
            for (int ks = 0; ks < 2; ++ks)
                a[mi][ks] = *reinterpret_cast<const bf16x8*>(
                    lsA + swz(QM*128 + wrr*64 + mi*16 + rl, ks*64 + lh*16));
    }
    if (LB) {
        #pragma unroll
        for (int ni = 0; ni < 2; ++ni)
            #pragma unroll
            for (int ks = 0; ks < 2; ++ks)
                b[ni][ks] = *reinterpret_cast<const bf16x8*>(
                    lsB + swz(QN*128 + wcc*32 + ni*16 + rl, ks*64 + lh*16));
    }
    __builtin_amdgcn_s_setprio(1);
    #pragma unroll
    for (int mi = 0; mi < 4; ++mi)
        #pragma unroll
        for (int ni = 0; ni < 2; ++ni)
            #pragma unroll
            for (int ks = 0; ks < 2; ++ks)
                acc[QM*2+QN][mi][ni] = __builtin_amdgcn_mfma_f32_16x16x32_bf16(
                    a[mi][ks], b[ni][ks], acc[QM*2+QN][mi][ni], 0, 0, 0);
    __builtin_amdgcn_s_setprio(0);
}

// 256x256xK GEMM core, 4-phase cadence (r8 = best measured): 1 half-tile
// staged per phase into the other buffer; PEND(4) per phase (never 0 in
// steady state). nt >= 2.
__device__ __forceinline__ void gemm256(const char* gA, const char* gB,
    size_t sA, size_t sB, int nt, char* ls, f32x4 (&acc)[4][4][2])
{
    const int tid = threadIdx.x, lane = tid & 63, wid = tid >> 6;
    const int wrr = wid >> 2, wcc = wid & 3;
    const int rl = lane & 15, lh = lane >> 4;
    char* bufA[2] = { ls,         ls + 65536 };
    char* bufB[2] = { ls + 32768, ls + 98304 };

    bf16x8 a[4][2];
    bf16x8 bb[2][2][2];   // bb[0]=B-half0 frags, bb[1]=B-half1 frags

    // prologue: tile 0, all 4 halves
    stage_half(bufA[0] + 0,     gA,                      sA, tid);
    stage_half(bufB[0] + 0,     gB,                      sB, tid);
    stage_half(bufB[0] + 16384, gB + (size_t)128 * sB,   sB, tid);
    stage_half(bufA[0] + 16384, gA + (size_t)128 * sA,   sA, tid);
    PEND(0);

    for (int u = 0; u < nt - 1; ++u) {
        const char* cA = bufA[u & 1];
        const char* cB = bufB[u & 1];
        char* nA = bufA[(u + 1) & 1];
        char* nB = bufB[(u + 1) & 1];
        const char* gAn = gA + (size_t)(u + 1) * 128;
        const char* gBn = gB + (size_t)(u + 1) * 128;

        stage_half(nA + 0,     gAn,                    sA, tid);
        phase8<0,0,true ,true >(cA, cB, wrr, wcc, rl, lh, a, bb[0], acc);
        PEND(4);
        stage_half(nB + 0,     gBn,                    sB, tid);
        phase8<0,1,false,true >(cA, cB, wrr, wcc, rl, lh, a, bb[1], acc);
        PEND(4);
        stage_half(nB + 16384, gBn + (size_t)128 * sB, sB, tid);
        phase8<1,1,true ,false>(cA, cB, wrr, wcc, rl, lh, a, bb[1], acc);
        PEND(4);
        stage_half(nA + 16384, gAn + (size_t)128 * sA, sA, tid);
        phase8<1,0,false,false>(cA, cB, wrr, wcc, rl, lh, a, bb[0], acc);
        PEND(4);
    }
    // final window: no staging; drain counted
    {
        const char* cA = bufA[(nt - 1) & 1];
        const char* cB = bufB[(nt - 1) & 1];
        phase8<0,0,true ,true >(cA, cB, wrr, wcc, rl, lh, a, bb[0], acc);
        PEND(2);
        phase8<0,1,false,true >(cA, cB, wrr, wcc, rl, lh, a, bb[1], acc);
        PEND(0);
        phase8<1,1,true ,false>(cA, cB, wrr, wcc, rl, lh, a, bb[1], acc);
        phase8<1,0,false,false>(cA, cB, wrr, wcc, rl, lh, a, bb[0], acc);
    }
}

// Epilogue index helpers: for quadrant q (QM=q>>1, QN=q&1):
//   row = QM*128 + (wid>>2)*64 + mi*16 + lh*4 + r
//   col = QN*128 + (wid&3)*32 + ni*16 + rl

// ---------------- K0a: X (f32) -> Xb (bf16), flat ----------------------------
__global__ __launch_bounds__(256) void cvt_x_kernel(
    const float* __restrict__ X, __bf16* __restrict__ Xb)
{
    const int n8 = (8 * S_LEN * E_DIM) / 8;
    for (int i = blockIdx.x * 256 + threadIdx.x; i < n8; i += gridDim.x * 256) {
        const float* p = X + (size_t)i * 8;
        float4 a = *reinterpret_cast<const float4*>(p);
        float4 b = *reinterpret_cast<const float4*>(p + 4);
        bf16x8 h = { f2bf(a.x), f2bf(a.y), f2bf(a.z), f2bf(a.w),
                     f2bf(b.x), f2bf(b.y), f2bf(b.z), f2bf(b.w) };
        *reinterpret_cast<bf16x8*>(Xb + (size_t)i * 8) = h;
    }
}

// ---------------- K0b: W (f32 [E][D]) -> Wt (bf16 [D][E]), 3 slices ----------
__global__ __launch_bounds__(256) void wt_kernel(
    const float* __restrict__ Wq, const float* __restrict__ Wk, const float* __restrict__ Wv,
    __bf16* __restrict__ Wt)
{
    __shared__ float t[64][68];
    const int z = blockIdx.z;
    const float* W = (z == 0) ? Wq : (z == 1) ? Wk : Wv;
    const int d0 = blockIdx.x * 64, e0 = blockIdx.y * 64;
    const int tid = threadIdx.x;

    const int er = tid >> 4, dc = (tid & 15) * 4;
    #pragma unroll
    for (int p = 0; p < 4; ++p) {
        int e = p * 16 + er;
        float4 v = *reinterpret_cast<const float4*>(W + (size_t)(e0 + e) * D_DIM + d0 + dc);
        *reinterpret_cast<float4*>(&t[e][dc]) = v;
    }
    __syncthreads();

    const int dl = tid >> 3, ec = (tid & 7) * 8;
    __bf16* O = Wt + (size_t)z * E_DIM * D_DIM;
    #pragma unroll
    for (int p = 0; p < 2; ++p) {
        int d = p * 32 + dl;
        bf16x8 h;
        #pragma unroll
        for (int j = 0; j < 8; ++j) h[j] = f2bf(t[ec + j][d]);
        *reinterpret_cast<bf16x8*>(O + (size_t)(d0 + d) * E_DIM + e0 + ec) = h;
    }
}

// ---------------- K1: QKV projection (V stored transposed) -------------------
__global__ __launch_bounds__(512, 2) void qkv_kernel(
    const __bf16* __restrict__ Xb, const __bf16* __restrict__ Wt,
    __bf16* __restrict__ Qb, __bf16* __restrict__ Kb, __bf16* __restrict__ Vt)
{
    __shared__ __align__(16) char ls[131072];
    int bx, mt, z;
    xcd_map(4, 64, 3, bx, mt, z);
    const int m0 = mt * 256, n0 = bx * 256;

    f32x4 acc[4][4][2] = {};
    gemm256((const char*)Xb + (size_t)m0 * (E_DIM * 2),
            (const char*)(Wt + (size_t)z * E_DIM * D_DIM) + (size_t)n0 * (E_DIM * 2),
            E_DIM * 2, E_DIM * 2, E_DIM / 64, ls, acc);

    const int tid = threadIdx.x, lane = tid & 63, wid = tid >> 6;
    const int wrr = wid >> 2, wcc = wid & 3;
    const int rl = lane & 15, lh = lane >> 4;

    if (z < 2) {
        __bf16* O = (z == 0) ? Qb : Kb;
        #pragma unroll
        for (int q = 0; q < 4; ++q) {
            #pragma unroll
            for (int mi = 0; mi < 4; ++mi) {
                int row = m0 + (q >> 1)*128 + wrr*64 + mi*16 + lh*4;
                #pragma unroll
                for (int ni = 0; ni < 2; ++ni) {
                    int col = n0 + (q & 1)*128 + wcc*32 + ni*16 + rl;
                    #pragma unroll
                    for (int r = 0; r < 4; ++r)
                        O[(size_t)(row + r) * D_DIM + col] = f2bf(acc[q][mi][ni][r]);
                }
            }
        }
    } else {
        const int bz = m0 >> 11;
        const int srow = m0 & 2047;
        __bf16* O = Vt + (size_t)bz * D_DIM * S_LEN;
        #pragma unroll
        for (int q = 0; q < 4; ++q) {
            #pragma unroll
            for (int mi = 0; mi < 4; ++mi) {
                int row = srow + (q >> 1)*128 + wrr*64 + mi*16 + lh*4;
                #pragma unroll
                for (int ni = 0; ni < 2; ++ni) {
                    int col = n0 + (q & 1)*128 + wcc*32 + ni*16 + rl;
                    bf16x4 h = { f2bf(acc[q][mi][ni][0]), f2bf(acc[q][mi][ni][1]),
                                 f2bf(acc[q][mi][ni][2]), f2bf(acc[q][mi][ni][3]) };
                    *reinterpret_cast<bf16x4*>(O + (size_t)col * S_LEN + row) = h;
                }
            }
        }
    }
}

// ---------------- K2: scores = QK^T/32, P = mask*exp(s), rowsums -------------
__global__ __launch_bounds__(512, 2) void qk_kernel(
    const __bf16* __restrict__ Qb, const __bf16* __restrict__ Kb,
    const int* __restrict__ mask, __bf16* __restrict__ P, float* __restrict__ rowsum)
{
    __shared__ __align__(16) char ls[131072];
    int kt, qt, bz;
    xcd_map(8, 8, 8, kt, qt, bz);   // each XCD owns one batch -> Q/K L2-local
    const int q0 = qt * 256, k0 = kt * 256;

    f32x4 acc[4][4][2] = {};
    gemm256((const char*)(Qb + (size_t)bz * S_LEN * D_DIM) + (size_t)q0 * (D_DIM * 2),
            (const char*)(Kb + (size_t)bz * S_LEN * D_DIM) + (size_t)k0 * (D_DIM * 2),
            D_DIM * 2, D_DIM * 2, D_DIM / 64, ls, acc);

    const int tid = threadIdx.x, lane = tid & 63, wid = tid >> 6;
    const int wrr = wid >> 2, wcc = wid & 3;
    const int rl = lane & 15, lh = lane >> 4;

    float rs[2][4][4] = {};
    const size_t mbase = (size_t)bz * S_LEN * S_LEN;
    #pragma unroll
    for (int q = 0; q < 4; ++q) {
        #pragma unroll
        for (int mi = 0; mi < 4; ++mi) {
            int row = q0 + (q >> 1)*128 + wrr*64 + mi*16 + lh*4;
            #pragma unroll
            for (int ni = 0; ni < 2; ++ni) {
                int col = k0 + (q & 1)*128 + wcc*32 + ni*16 + rl;
                #pragma unroll
                for (int r = 0; r < 4; ++r) {
                    float s = acc[q][mi][ni][r] * 0.03125f;
                    int mk = mask[mbase + (size_t)(row + r) * S_LEN + col];
                    float pv = mk ? __expf(s) : 0.0f;
                    rs[q >> 1][mi][r] += pv;
                    P[mbase + (size_t)(row + r) * S_LEN + col] = f2bf(pv);
                }
            }
        }
    }
    #pragma unroll
    for (int h = 0; h < 2; ++h) {
        #pragma unroll
        for (int mi = 0; mi < 4; ++mi) {
            #pragma unroll
            for (int r = 0; r < 4; ++r) {
                float v = rs[h][mi][r];
                v += __shfl_xor(v, 1);
                v += __shfl_xor(v, 2);
                v += __shfl_xor(v, 4);
                v += __shfl_xor(v, 8);
                if (rl == 0)
                    atomicAdd(&rowsum[bz * S_LEN + q0 + h*128 + wrr*64 + mi*16 + lh*4 + r], v);
            }
        }
    }
}

// ---------------- K3: out = (P @ V) / rowsum ---------------------------------
__global__ __launch_bounds__(512, 2) void pv_kernel(
    const __bf16* __restrict__ P, const __bf16* __restrict__ Vt,
    const float* __restrict__ rowsum, float* __restrict__ out)
{
    __shared__ __align__(16) char ls[131072];
    int dt, qt, bz;
    xcd_map(4, 8, 8, dt, qt, bz);   // each XCD owns one batch -> P/Vt L2-local
    const int q0 = qt * 256, d0c = dt * 256;

    f32x4 acc[4][4][2] = {};
    gemm256((const char*)(P  + (size_t)bz * S_LEN * S_LEN) + (size_t)q0  * (S_LEN * 2),
            (const char*)(Vt + (size_t)bz * D_DIM * S_LEN) + (size_t)d0c * (S_LEN * 2),
            S_LEN * 2, S_LEN * 2, S_LEN / 64, ls, acc);

    const int tid = threadIdx.x, lane = tid & 63, wid = tid >> 6;
    const int wrr = wid >> 2, wcc = wid & 3;
    const int rl = lane & 15, lh = lane >> 4;

    float* Ob = out + (size_t)bz * S_LEN * D_DIM;
    #pragma unroll
    for (int q = 0; q < 4; ++q) {
        #pragma unroll
        for (int mi = 0; mi < 4; ++mi) {
            int row = q0 + (q >> 1)*128 + wrr*64 + mi*16 + lh*4;
            float inv[4];
            #pragma unroll
            for (int r = 0; r < 4; ++r)
                inv[r] = 1.0f / (rowsum[bz * S_LEN + row + r] + 1e-20f);
            #pragma unroll
            for (int ni = 0; ni < 2; ++ni) {
                int col = d0c + (q & 1)*128 + wcc*32 + ni*16 + rl;
                #pragma unroll
                for (int r = 0; r < 4; ++r)
                    Ob[(size_t)(row + r) * D_DIM + col] = acc[q][mi][ni][r] * inv[r];
            }
        }
    }
}

extern "C" void kernel_launch(void* const* d_in, const int* in_sizes, int n_in,
                              void* d_out, int out_size, void* d_ws, size_t ws_size,
                              hipStream_t stream) {
    const float* x    = (const float*)d_in[0];
    const int*   mask = (const int*)  d_in[1];
    const float* Wq   = (const float*)d_in[2];
    const float* Wk   = (const float*)d_in[3];
    const float* Wv   = (const float*)d_in[4];
    float* out = (float*)d_out;

    char* ws = (char*)d_ws;
    const size_t SZ_QKV = (size_t)8 * S_LEN * D_DIM * 2;      // 32 MB each (bf16)
    const size_t SZ_P   = (size_t)8 * S_LEN * S_LEN * 2;      // 64 MB
    __bf16* Qb = (__bf16*)(ws);
    __bf16* Kb = (__bf16*)(ws + SZ_QKV);
    __bf16* Vt = (__bf16*)(ws + 2 * SZ_QKV);
    char*   pbase = ws + 3 * SZ_QKV;
    __bf16* P  = (__bf16*)pbase;
    // Xb/Wt alias the P region: fully consumed by qkv_kernel before qk_kernel
    // writes P (stream-ordered), saves 38 MB.
    __bf16* Xb = (__bf16*)pbase;                              // 32 MB
    __bf16* Wt = (__bf16*)(pbase + (size_t)8 * S_LEN * E_DIM * 2);  // 6 MB
    float* rowsum = (float*)(ws + 3 * SZ_QKV + SZ_P);
    const size_t need = 3 * SZ_QKV + SZ_P + (size_t)8 * S_LEN * 4;
    if (ws_size < need) return;

    hipMemsetAsync(rowsum, 0, (size_t)8 * S_LEN * 4, stream);
    cvt_x_kernel<<<2048, 256, 0, stream>>>(x, Xb);
    wt_kernel  <<<dim3(16, 16, 3), 256, 0, stream>>>(Wq, Wk, Wv, Wt);
    qkv_kernel <<<dim3(4, 64, 3), 512, 0, stream>>>(Xb, Wt, Qb, Kb, Vt);
    qk_kernel  <<<dim3(8, 8, 8),  512, 0, stream>>>(Qb, Kb, mask, P, rowsum);
    pv_kernel  <<<dim3(4, 8, 8),  512, 0, stream>>>(P, Vt, rowsum, out);
}